// Round 2
// baseline (496.158 us; speedup 1.0000x reference)
//
#include <hip/hip_runtime.h>
#include <math.h>

#define T_ 6
#define LQ_ 300
#define C_ 256
#define NH_ 8
#define HD_ 32
#define NL_ 4
#define PC_ 4
#define TW_ 2
#define PT_ 2
#define DFF_ 1024
#define LIN_ 16320
#define NQ_ (T_*LQ_)   /* 1800 */

typedef unsigned int uint32;

__device__ __forceinline__ float b2f(unsigned short u) {
    union { float f; unsigned i; } x; x.i = ((unsigned)u) << 16; return x.f;
}
__device__ __forceinline__ unsigned short f2b(float f) {
    union { float f; unsigned i; } x; x.f = f;
    unsigned r = x.i + 0x7fffu + ((x.i >> 16) & 1u);
    return (unsigned short)(r >> 16);
}
__device__ __forceinline__ uint32 pack2(float a, float b) {
    return (uint32)f2b(a) | ((uint32)f2b(b) << 16);
}

typedef __bf16 bf16x8 __attribute__((ext_vector_type(8)));
typedef float  f32x4  __attribute__((ext_vector_type(4)));

// ---------------------------------------------------------------------------
// out = a + b (fp32, float4 vectorized)
// ---------------------------------------------------------------------------
__global__ void add_f32(const float4* __restrict__ a, const float4* __restrict__ b,
                        float4* __restrict__ o, int n4) {
    int i = blockIdx.x * 256 + threadIdx.x;
    if (i < n4) {
        float4 x = a[i], y = b[i];
        o[i] = make_float4(x.x + y.x, x.y + y.y, x.z + y.z, x.w + y.w);
    }
}

// ---------------------------------------------------------------------------
// C[M,N] = act(A[M,K] @ B[N,K]^T + bias[N]); A,B,bias fp32, C fp32 or bf16.
// fp32 global -> bf16 LDS conversion in the staging copy; bf16 MFMA; fp32 acc.
// Block tile 64x64, BK=32, 4 waves each 32x32 (2x2 of 16x16x32 MFMA).
// LDS leading stride 40 shorts (80B) -> only 2-way bank aliasing (free).
// ---------------------------------------------------------------------------
template<bool RELU, bool OUT_BF16>
__global__ __launch_bounds__(256) void gemm_bt(
        const float* __restrict__ A, const float* __restrict__ B,
        const float* __restrict__ bias, void* __restrict__ Cmat,
        int M, int N, int K) {
    constexpr int LDA = 40;
    __shared__ __align__(16) unsigned short As[64 * LDA];
    __shared__ __align__(16) unsigned short Bs[64 * LDA];
    int tid  = threadIdx.x;
    int wave = tid >> 6, lane = tid & 63;
    int bm = blockIdx.x * 64, bn = blockIdx.y * 64;
    int wm = (wave >> 1) * 32, wn = (wave & 1) * 32;

    f32x4 acc00 = {0.f,0.f,0.f,0.f}, acc01 = {0.f,0.f,0.f,0.f};
    f32x4 acc10 = {0.f,0.f,0.f,0.f}, acc11 = {0.f,0.f,0.f,0.f};

    int srow = tid >> 2, scol = (tid & 3) * 8;
    int arow = bm + srow;
    const bool aval = arow < M;
    const size_t aoff = (size_t)arow * K + scol;
    const size_t boff = (size_t)(bn + srow) * K + scol;

    int fr = lane & 15, quad = lane >> 4;
    const unsigned short* pa0 = As + (wm + fr) * LDA + quad * 8;
    const unsigned short* pa1 = pa0 + 16 * LDA;
    const unsigned short* pb0 = Bs + (wn + fr) * LDA + quad * 8;
    const unsigned short* pb1 = pb0 + 16 * LDA;

    for (int k0 = 0; k0 < K; k0 += 32) {
        float4 a0v = {0,0,0,0}, a1v = {0,0,0,0};
        if (aval) {
            a0v = *(const float4*)(A + aoff + k0);
            a1v = *(const float4*)(A + aoff + k0 + 4);
        }
        float4 b0v = *(const float4*)(B + boff + k0);
        float4 b1v = *(const float4*)(B + boff + k0 + 4);
        uint4 ap, bp;
        ap.x = pack2(a0v.x, a0v.y); ap.y = pack2(a0v.z, a0v.w);
        ap.z = pack2(a1v.x, a1v.y); ap.w = pack2(a1v.z, a1v.w);
        bp.x = pack2(b0v.x, b0v.y); bp.y = pack2(b0v.z, b0v.w);
        bp.z = pack2(b1v.x, b1v.y); bp.w = pack2(b1v.z, b1v.w);
        __syncthreads();
        *(uint4*)(As + srow * LDA + scol) = ap;
        *(uint4*)(Bs + srow * LDA + scol) = bp;
        __syncthreads();
        bf16x8 a0 = *(const bf16x8*)pa0;
        bf16x8 a1 = *(const bf16x8*)pa1;
        bf16x8 b0 = *(const bf16x8*)pb0;
        bf16x8 b1 = *(const bf16x8*)pb1;
        acc00 = __builtin_amdgcn_mfma_f32_16x16x32_bf16(a0, b0, acc00, 0, 0, 0);
        acc01 = __builtin_amdgcn_mfma_f32_16x16x32_bf16(a0, b1, acc01, 0, 0, 0);
        acc10 = __builtin_amdgcn_mfma_f32_16x16x32_bf16(a1, b0, acc10, 0, 0, 0);
        acc11 = __builtin_amdgcn_mfma_f32_16x16x32_bf16(a1, b1, acc11, 0, 0, 0);
    }

    // C/D layout: n = lane&15, m = quad*4 + reg  [measured m89/m91]
    int n0 = bn + wn + fr;
    int n1 = n0 + 16;
    float bias0 = bias[n0], bias1 = bias[n1];
    int mbase = bm + wm + quad * 4;
    #pragma unroll
    for (int r = 0; r < 4; ++r) {
        int m0 = mbase + r;
        int m1 = m0 + 16;
        float v00 = acc00[r] + bias0, v01 = acc01[r] + bias1;
        float v10 = acc10[r] + bias0, v11 = acc11[r] + bias1;
        if (RELU) {
            v00 = fmaxf(v00, 0.f); v01 = fmaxf(v01, 0.f);
            v10 = fmaxf(v10, 0.f); v11 = fmaxf(v11, 0.f);
        }
        if (OUT_BF16) {
            unsigned short* Cp = (unsigned short*)Cmat;
            if (m0 < M) { Cp[(size_t)m0 * N + n0] = f2b(v00); Cp[(size_t)m0 * N + n1] = f2b(v01); }
            if (m1 < M) { Cp[(size_t)m1 * N + n0] = f2b(v10); Cp[(size_t)m1 * N + n1] = f2b(v11); }
        } else {
            float* Cp = (float*)Cmat;
            if (m0 < M) { Cp[(size_t)m0 * N + n0] = v00; Cp[(size_t)m0 * N + n1] = v01; }
            if (m1 < M) { Cp[(size_t)m1 * N + n0] = v10; Cp[(size_t)m1 * N + n1] = v11; }
        }
    }
}

// ---------------------------------------------------------------------------
// Self-attention: one block per (t, h, 32-query chunk). K/V rows for this
// (t,h) staged into LDS as packed-bf16 pairs, row stride 17 uint32 (conflict-
// free). Each wave handles 8 queries: wave-parallel score pass + softmax,
// then lane=(dim-pair, key-quarter) AV pass.
// qk: (1800, 512) fp32, q cols [0,256), k cols [256,512). vb: (1800,256) fp32.
// sain: (1800, 256) fp32 (channel = h*32+d).
// ---------------------------------------------------------------------------
__global__ __launch_bounds__(256) void attn_kernel(
        const float* __restrict__ qk, const float* __restrict__ vb,
        float* __restrict__ sain) {
    __shared__ uint32 Ksu[300 * 17];
    __shared__ uint32 Vsu[300 * 17];
    __shared__ float  Qs[32 * 32];
    __shared__ float  ps[4][304];
    int t = blockIdx.x / NH_, h = blockIdx.x % NH_;
    int q0 = blockIdx.y * 32;
    int tid = threadIdx.x;

    for (int idx = tid; idx < 300 * 16; idx += 256) {
        int row = idx >> 4, cc = idx & 15;
        float2 kv = *(const float2*)(qk + (size_t)(t * 300 + row) * 512 + 256 + h * 32 + 2 * cc);
        float2 vv = *(const float2*)(vb + (size_t)(t * 300 + row) * 256 + h * 32 + 2 * cc);
        Ksu[row * 17 + cc] = pack2(kv.x, kv.y);
        Vsu[row * 17 + cc] = pack2(vv.x, vv.y);
    }
    for (int idx = tid; idx < 1024; idx += 256) {
        int row = idx >> 5, d = idx & 31;
        int q = q0 + row;
        Qs[idx] = (q < 300) ? qk[(size_t)(t * 300 + q) * 512 + h * 32 + d] : 0.f;
    }
    __syncthreads();

    int wavei = tid >> 6, lane = tid & 63;
    const float scale = 0.17677669529663687f;  // 1/sqrt(32)

    for (int i = 0; i < 8; ++i) {               // uniform loop: barriers legal
        int q = q0 + wavei * 8 + i;
        int ql = wavei * 8 + i;
        float qv[32];
        #pragma unroll
        for (int d = 0; d < 32; ++d) qv[d] = Qs[ql * 32 + d];

        float sc[5], mx = -1e30f;
        #pragma unroll
        for (int m = 0; m < 5; ++m) {
            int k = lane + 64 * m;
            float s = -1e30f;
            if (k < 300) {
                s = 0.f;
                #pragma unroll
                for (int dd = 0; dd < 16; ++dd) {
                    uint32 u = Ksu[k * 17 + dd];
                    s += qv[2 * dd]     * b2f((unsigned short)u)
                       + qv[2 * dd + 1] * b2f((unsigned short)(u >> 16));
                }
                s *= scale;
            }
            sc[m] = s; mx = fmaxf(mx, s);
        }
        #pragma unroll
        for (int off = 1; off < 64; off <<= 1) mx = fmaxf(mx, __shfl_xor(mx, off));
        float sum = 0.f;
        #pragma unroll
        for (int m = 0; m < 5; ++m) {
            int k = lane + 64 * m;
            float ev = (k < 300) ? __expf(sc[m] - mx) : 0.f;
            if (k < 300) ps[wavei][k] = ev;
            sum += ev;
        }
        #pragma unroll
        for (int off = 1; off < 64; off <<= 1) sum += __shfl_xor(sum, off);
        float inv = 1.f / sum;
        __syncthreads();   // ps visible

        int e16 = lane & 15, kh = lane >> 4;
        float ox = 0.f, oy = 0.f;
        int kbeg = kh * 75;
        for (int k = kbeg; k < kbeg + 75; ++k) {
            float p = ps[wavei][k];
            uint32 u = Vsu[k * 17 + e16];
            ox += p * b2f((unsigned short)u);
            oy += p * b2f((unsigned short)(u >> 16));
        }
        ox += __shfl_xor(ox, 16); ox += __shfl_xor(ox, 32);
        oy += __shfl_xor(oy, 16); oy += __shfl_xor(oy, 32);
        if (q < 300 && kh == 0) {
            *(float2*)(sain + (size_t)(t * 300 + q) * 256 + h * 32 + 2 * e16)
                = make_float2(ox * inv, oy * inv);
        }
        __syncthreads();   // protect ps before next iteration overwrites
    }
}

// ---------------------------------------------------------------------------
// aw softmax (32-wide, fused) + deformable bilinear sampling.
// One block per (t,q); thread = (h = tid>>5, d = tid&31). Sample weights
// broadcast via width-32 shuffles. value: (T, LIN, NH, HD) bf16, rest fp32.
// ---------------------------------------------------------------------------
__global__ __launch_bounds__(256) void sample_kernel(
        const float* __restrict__ awl,   const float* __restrict__ refp,
        const float* __restrict__ cfo,   const float* __restrict__ ofo,
        const float* __restrict__ soffo, const float* __restrict__ toffo,
        const unsigned short* __restrict__ value, float* __restrict__ samp) {
    const int HL[4] = {96, 48, 24, 12};
    const int WL[4] = {128, 64, 32, 16};
    const int ST[4] = {0, 12288, 15360, 16128};
    int b = blockIdx.x;
    int t = b / LQ_;
    int tid = threadIdx.x, h = tid >> 5, d = tid & 31;
    size_t row = (size_t)b;

    float logit = awl[row * 256 + h * 32 + d];
    float mx = logit;
    #pragma unroll
    for (int off = 16; off >= 1; off >>= 1) mx = fmaxf(mx, __shfl_xor(mx, off, 32));
    float e = __expf(logit - mx);
    float s = e;
    #pragma unroll
    for (int off = 16; off >= 1; off >>= 1) s += __shfl_xor(s, off, 32);
    float myw = e / s;

    float acc = 0.f;
    for (int smp = 0; smp < 32; ++smp) {
        int l = smp >> 3, j = smp & 7;
        float wgt = __shfl(myw, smp, 32);
        int Hl = HL[l], Wl = WL[l], st = ST[l];
        float rx = refp[(row * 4 + l) * 2 + 0];
        float ry = refp[(row * 4 + l) * 2 + 1];
        float lx, ly; int frame;
        if (j < 4) {
            lx = rx + cfo[(row * 4 + l) * 2 + 0]
               + soffo[row * 256 + h * 32 + l * 8 + j * 2 + 0] / (float)Wl;
            ly = ry + cfo[(row * 4 + l) * 2 + 1]
               + soffo[row * 256 + h * 32 + l * 8 + j * 2 + 1] / (float)Hl;
            frame = t;
        } else {
            int wi = (j - 4) >> 1, p = (j - 4) & 1;
            lx = rx + ofo[((row * 2 + wi) * 4 + l) * 2 + 0]
               + toffo[row * 256 + h * 32 + l * 8 + wi * 4 + p * 2 + 0] / (float)Wl;
            ly = ry + ofo[((row * 2 + wi) * 4 + l) * 2 + 1]
               + toffo[row * 256 + h * 32 + l * 8 + wi * 4 + p * 2 + 1] / (float)Hl;
            frame = t + (wi == 0 ? -1 : 1);
            frame = frame < 0 ? 0 : (frame > T_ - 1 ? T_ - 1 : frame);
        }
        float x = lx * (float)Wl - 0.5f, y = ly * (float)Hl - 0.5f;
        float xf = floorf(x), yf = floorf(y);
        float wx = x - xf, wy = y - yf;
        int x0 = (int)xf, y0 = (int)yf;
        float sacc = 0.f;
        size_t base = ((size_t)frame * LIN_ + st) * 256 + h * 32 + d;
        #pragma unroll
        for (int cy = 0; cy < 2; ++cy) {
            int yi = y0 + cy;
            if (yi < 0 || yi >= Hl) continue;
            float wyv = cy ? wy : 1.f - wy;
            #pragma unroll
            for (int cx = 0; cx < 2; ++cx) {
                int xi = x0 + cx;
                if (xi < 0 || xi >= Wl) continue;
                float wv = wyv * (cx ? wx : 1.f - wx);
                sacc += wv * b2f(value[base + (size_t)(yi * Wl + xi) * 256]);
            }
        }
        acc += wgt * sacc;
    }
    samp[row * 256 + h * 32 + d] = acc;
}

// ---------------------------------------------------------------------------
// out = LN(x + y)*g + b ; optional out2 = out + pos. One block per row, c=tid.
// All fp32.
// ---------------------------------------------------------------------------
__global__ __launch_bounds__(256) void ln_kernel(
        const float* __restrict__ x, const float* __restrict__ y,
        const float* __restrict__ g, const float* __restrict__ bb,
        float* __restrict__ out,
        const float* __restrict__ pos, float* __restrict__ out2) {
    int row = blockIdx.x, c = threadIdx.x;
    size_t idx = (size_t)row * 256 + c;
    float v = x[idx] + y[idx];
    float s = v;
    #pragma unroll
    for (int off = 1; off < 64; off <<= 1) s += __shfl_xor(s, off);
    __shared__ float red[4];
    int wv = c >> 6;
    if ((c & 63) == 0) red[wv] = s;
    __syncthreads();
    float mean = (red[0] + red[1] + red[2] + red[3]) * (1.0f / 256.0f);
    float dv = v - mean;
    float s2 = dv * dv;
    #pragma unroll
    for (int off = 1; off < 64; off <<= 1) s2 += __shfl_xor(s2, off);
    __syncthreads();
    if ((c & 63) == 0) red[wv] = s2;
    __syncthreads();
    float var = (red[0] + red[1] + red[2] + red[3]) * (1.0f / 256.0f);
    float o = dv * rsqrtf(var + 1e-5f) * g[c] + bb[c];
    out[idx] = o;
    if (out2) out2[idx] = o + pos[idx];
}

// ---------------------------------------------------------------------------
extern "C" void kernel_launch(void* const* d_in, const int* in_sizes, int n_in,
                              void* d_out, int out_size, void* d_ws, size_t ws_size,
                              hipStream_t stream) {
    (void)in_sizes; (void)n_in; (void)out_size; (void)ws_size;
    typedef const float* cfp;
    cfp tgt   = (cfp)d_in[0];
    cfp qpos  = (cfp)d_in[1];
    cfp refp  = (cfp)d_in[2];
    cfp cfo   = (cfp)d_in[3];
    cfp ofo   = (cfp)d_in[4];
    cfp src   = (cfp)d_in[5];
    cfp in_proj_w = (cfp)d_in[9];
    cfp in_proj_b = (cfp)d_in[10];
    cfp sa_out_w  = (cfp)d_in[11];
    cfp sa_out_b  = (cfp)d_in[12];
    cfp n1g = (cfp)d_in[13], n1b = (cfp)d_in[14];
    cfp n2g = (cfp)d_in[15], n2b = (cfp)d_in[16];
    cfp n3g = (cfp)d_in[17], n3b = (cfp)d_in[18];
    cfp value_w = (cfp)d_in[19], value_b = (cfp)d_in[20];
    cfp soff_w = (cfp)d_in[21], soff_b = (cfp)d_in[22];
    cfp toff_w = (cfp)d_in[23], toff_b = (cfp)d_in[24];
    cfp attn_w = (cfp)d_in[25], attn_b = (cfp)d_in[26];
    cfp cross_w = (cfp)d_in[27], cross_b = (cfp)d_in[28];
    cfp lin1_w = (cfp)d_in[29], lin1_b = (cfp)d_in[30];
    cfp lin2_w = (cfp)d_in[31], lin2_b = (cfp)d_in[32];

    // ---- workspace arena (lifetime-aliased; all launches are stream-ordered)
    char* wp = (char*)d_ws;
    const size_t ROWB = (size_t)NQ_ * 256 * 4;           // 1,843,200 B
    unsigned short* value = (unsigned short*)wp;          // bf16, 25 MB
    wp += (size_t)T_ * LIN_ * 256 * 2;
    float* bigreg = (float*)wp;  wp += 4 * ROWB;          // qin|qkb|vbuf, reused by ff1
    float* qin  = bigreg;                                 // NQ x 256
    float* qkb  = bigreg + (size_t)NQ_ * 256;             // NQ x 512
    float* vbuf = bigreg + (size_t)NQ_ * 768;             // NQ x 256
    float* ff1  = bigreg;                                 // NQ x 1024 (after attn)
    float* sain   = (float*)wp; wp += ROWB;               // reused by awl
    float* awl    = sain;
    float* sap    = (float*)wp; wp += ROWB;               // reused by soffo
    float* soffo  = sap;
    float* tgt2   = (float*)wp; wp += ROWB;               // reused by ff2
    float* ff2    = tgt2;
    float* qc     = (float*)wp; wp += ROWB;               // reused by samp
    float* samp   = qc;
    float* toffo  = (float*)wp; wp += ROWB;
    float* crossp = (float*)wp; wp += ROWB;
    float* tgt3   = (float*)wp; wp += ROWB;

    dim3 blk(256);
    const int mb = (NQ_ + 63) / 64;  // 29

    // q = tgt + query_pos
    add_f32<<<dim3((NQ_ * 64 + 255) / 256), blk, 0, stream>>>(
        (const float4*)tgt, (const float4*)qpos, (float4*)qin, NQ_ * 64);
    // q/k projection (N=512)
    gemm_bt<false,false><<<dim3(mb, 8), blk, 0, stream>>>(qin, in_proj_w, in_proj_b, qkb, NQ_, 512, 256);
    // v projection from tgt
    gemm_bt<false,false><<<dim3(mb, 4), blk, 0, stream>>>(tgt, in_proj_w + 512 * 256, in_proj_b + 512,
                                                          vbuf, NQ_, 256, 256);
    // self attention
    attn_kernel<<<dim3(T_ * NH_, 10), blk, 0, stream>>>(qkb, vbuf, sain);
    // sa out projection
    gemm_bt<false,false><<<dim3(mb, 4), blk, 0, stream>>>(sain, sa_out_w, sa_out_b, sap, NQ_, 256, 256);
    // tgt2 = LN(tgt + sa, norm2); qc = tgt2 + qpos
    ln_kernel<<<dim3(NQ_), blk, 0, stream>>>(tgt, sap, n2g, n2b, tgt2, qpos, qc);
    // offset / attn-weight projections
    gemm_bt<false,false><<<dim3(mb, 4), blk, 0, stream>>>(qc, soff_w, soff_b, soffo, NQ_, 256, 256);
    gemm_bt<false,false><<<dim3(mb, 4), blk, 0, stream>>>(qc, toff_w, toff_b, toffo, NQ_, 256, 256);
    gemm_bt<false,false><<<dim3(mb, 4), blk, 0, stream>>>(qc, attn_w, attn_b, awl, NQ_, 256, 256);
    // value projection (big GEMM, bf16 out): src (97920 x 256)
    gemm_bt<false,true><<<dim3((T_ * LIN_) / 64, 4), blk, 0, stream>>>(src, value_w, value_b, value,
                                                                       T_ * LIN_, 256, 256);
    // fused aw-softmax + deformable sampling
    sample_kernel<<<dim3(NQ_), blk, 0, stream>>>(awl, refp, cfo, ofo, soffo, toffo, value, samp);
    // cross projection
    gemm_bt<false,false><<<dim3(mb, 4), blk, 0, stream>>>(samp, cross_w, cross_b, crossp, NQ_, 256, 256);
    // tgt3 = LN(tgt2 + cross, norm1)
    ln_kernel<<<dim3(NQ_), blk, 0, stream>>>(tgt2, crossp, n1g, n1b, tgt3, nullptr, nullptr);
    // FFN
    gemm_bt<true,false><<<dim3(mb, 16), blk, 0, stream>>>(tgt3, lin1_w, lin1_b, ff1, NQ_, 1024, 256);
    gemm_bt<false,false><<<dim3(mb, 4), blk, 0, stream>>>(ff1, lin2_w, lin2_b, ff2, NQ_, 256, 1024);
    // out = LN(tgt3 + ff, norm3)
    ln_kernel<<<dim3(NQ_), blk, 0, stream>>>(tgt3, ff2, n3g, n3b, (float*)d_out, nullptr, nullptr);
}

// Round 3
// 404.893 us; speedup vs baseline: 1.2254x; 1.2254x over previous
//
#include <hip/hip_runtime.h>
#include <math.h>

#define T_ 6
#define LQ_ 300
#define C_ 256
#define NH_ 8
#define HD_ 32
#define NL_ 4
#define PC_ 4
#define TW_ 2
#define PT_ 2
#define DFF_ 1024
#define LIN_ 16320
#define NQ_ (T_*LQ_)   /* 1800 */

typedef unsigned int uint32;
typedef unsigned short us;

__device__ __forceinline__ float b2f(us u) {
    union { float f; unsigned i; } x; x.i = ((unsigned)u) << 16; return x.f;
}
__device__ __forceinline__ us f2b(float f) {
    union { float f; unsigned i; } x; x.f = f;
    unsigned r = x.i + 0x7fffu + ((x.i >> 16) & 1u);
    return (us)(r >> 16);
}
__device__ __forceinline__ uint32 pack2(float a, float b) {
    return (uint32)f2b(a) | ((uint32)f2b(b) << 16);
}

typedef __bf16 bf16x8 __attribute__((ext_vector_type(8)));
typedef float  f32x4  __attribute__((ext_vector_type(4)));

// ---------------------------------------------------------------------------
// out = a + b (fp32, float4)
// ---------------------------------------------------------------------------
__global__ void add_f32(const float4* __restrict__ a, const float4* __restrict__ b,
                        float4* __restrict__ o, int n4) {
    int i = blockIdx.x * 256 + threadIdx.x;
    if (i < n4) {
        float4 x = a[i], y = b[i];
        o[i] = make_float4(x.x + y.x, x.y + y.y, x.z + y.z, x.w + y.w);
    }
}

// ---------------------------------------------------------------------------
// 64x64-tile GEMM core: C[bm:bm+64, cn0:cn0+64] = A[bm:,:K] @ Bw[0:64,:K]^T
// + bias.  ALL K staging loads (per 256-chunk) issued upfront into registers
// -> one memory round trip per 256 K instead of 8 (latency fix for the
// M=1800 GEMMs that run at ~1 block/CU).
// ---------------------------------------------------------------------------
template<bool RELU>
__device__ __forceinline__ void gemm64_core(
        us* As, us* Bs,
        const float* __restrict__ A, const float* __restrict__ Bw,
        const float* __restrict__ bias, float* __restrict__ Cmat,
        int ldc, int cn0, int M, int K) {
    constexpr int LDA = 40;
    int tid  = threadIdx.x;
    int wave = tid >> 6, lane = tid & 63;
    int bm = blockIdx.x * 64;
    int wm = (wave >> 1) * 32, wn = (wave & 1) * 32;

    f32x4 acc00 = {0.f,0.f,0.f,0.f}, acc01 = {0.f,0.f,0.f,0.f};
    f32x4 acc10 = {0.f,0.f,0.f,0.f}, acc11 = {0.f,0.f,0.f,0.f};

    int srow = tid >> 2, scol = (tid & 3) * 8;
    int arow = bm + srow;
    const bool aval = arow < M;
    const size_t aoff = (size_t)arow * K + scol;
    const size_t boff = (size_t)srow * K + scol;

    int fr = lane & 15, quad = lane >> 4;
    const us* pa0 = As + (wm + fr) * LDA + quad * 8;
    const us* pa1 = pa0 + 16 * LDA;
    const us* pb0 = Bs + (wn + fr) * LDA + quad * 8;
    const us* pb1 = pb0 + 16 * LDA;

    for (int k0 = 0; k0 < K; k0 += 256) {
        float4 ar[8][2], br[8][2];
        #pragma unroll
        for (int c = 0; c < 8; ++c) {
            int kk = k0 + c * 32;
            if (aval) {
                ar[c][0] = *(const float4*)(A + aoff + kk);
                ar[c][1] = *(const float4*)(A + aoff + kk + 4);
            } else {
                ar[c][0] = make_float4(0.f,0.f,0.f,0.f);
                ar[c][1] = make_float4(0.f,0.f,0.f,0.f);
            }
            br[c][0] = *(const float4*)(Bw + boff + kk);
            br[c][1] = *(const float4*)(Bw + boff + kk + 4);
        }
        #pragma unroll
        for (int c = 0; c < 8; ++c) {
            uint4 ap, bp;
            ap.x = pack2(ar[c][0].x, ar[c][0].y); ap.y = pack2(ar[c][0].z, ar[c][0].w);
            ap.z = pack2(ar[c][1].x, ar[c][1].y); ap.w = pack2(ar[c][1].z, ar[c][1].w);
            bp.x = pack2(br[c][0].x, br[c][0].y); bp.y = pack2(br[c][0].z, br[c][0].w);
            bp.z = pack2(br[c][1].x, br[c][1].y); bp.w = pack2(br[c][1].z, br[c][1].w);
            __syncthreads();
            *(uint4*)(As + srow * LDA + scol) = ap;
            *(uint4*)(Bs + srow * LDA + scol) = bp;
            __syncthreads();
            bf16x8 a0 = *(const bf16x8*)pa0;
            bf16x8 a1 = *(const bf16x8*)pa1;
            bf16x8 b0 = *(const bf16x8*)pb0;
            bf16x8 b1 = *(const bf16x8*)pb1;
            acc00 = __builtin_amdgcn_mfma_f32_16x16x32_bf16(a0, b0, acc00, 0, 0, 0);
            acc01 = __builtin_amdgcn_mfma_f32_16x16x32_bf16(a0, b1, acc01, 0, 0, 0);
            acc10 = __builtin_amdgcn_mfma_f32_16x16x32_bf16(a1, b0, acc10, 0, 0, 0);
            acc11 = __builtin_amdgcn_mfma_f32_16x16x32_bf16(a1, b1, acc11, 0, 0, 0);
        }
    }

    // C/D layout: n = lane&15, m = quad*4 + reg  [measured m89/m91]
    int n0l = wn + fr, n1l = n0l + 16;
    float bias0 = bias[n0l], bias1 = bias[n1l];
    int mbase = bm + wm + quad * 4;
    #pragma unroll
    for (int r = 0; r < 4; ++r) {
        int m0 = mbase + r, m1 = m0 + 16;
        float v00 = acc00[r] + bias0, v01 = acc01[r] + bias1;
        float v10 = acc10[r] + bias0, v11 = acc11[r] + bias1;
        if (RELU) {
            v00 = fmaxf(v00, 0.f); v01 = fmaxf(v01, 0.f);
            v10 = fmaxf(v10, 0.f); v11 = fmaxf(v11, 0.f);
        }
        if (m0 < M) {
            Cmat[(size_t)m0 * ldc + cn0 + n0l] = v00;
            Cmat[(size_t)m0 * ldc + cn0 + n1l] = v01;
        }
        if (m1 < M) {
            Cmat[(size_t)m1 * ldc + cn0 + n0l] = v10;
            Cmat[(size_t)m1 * ldc + cn0 + n1l] = v11;
        }
    }
}

// plain wrapper
template<bool RELU>
__global__ __launch_bounds__(256, 2) void gemm_std(
        const float* __restrict__ A, const float* __restrict__ W,
        const float* __restrict__ bias, float* __restrict__ C,
        int M, int N, int K) {
    __shared__ __align__(16) us As[64 * 40];
    __shared__ __align__(16) us Bs[64 * 40];
    int cn0 = blockIdx.y * 64;
    gemm64_core<RELU>(As, Bs, A, W + (size_t)cn0 * K, bias + cn0, C, N, cn0, M, K);
}

// fused q/k (from qin) + v (from tgt) projection. grid.y = 12.
__global__ __launch_bounds__(256, 2) void gemm_qkv(
        const float* __restrict__ qin, const float* __restrict__ tgt,
        const float* __restrict__ w, const float* __restrict__ b,
        float* __restrict__ qkb, float* __restrict__ vbuf) {
    __shared__ __align__(16) us As[64 * 40];
    __shared__ __align__(16) us Bs[64 * 40];
    int y = blockIdx.y;
    const float* A; const float* W; const float* bias; float* O; int ldc, cn0;
    if (y < 8) {
        A = qin; W = w + (size_t)y * 64 * 256; bias = b + y * 64;
        O = qkb; ldc = 512; cn0 = y * 64;
    } else {
        int yy = y - 8;
        A = tgt; W = w + (size_t)(512 + yy * 64) * 256; bias = b + 512 + yy * 64;
        O = vbuf; ldc = 256; cn0 = yy * 64;
    }
    gemm64_core<false>(As, Bs, A, W, bias, O, ldc, cn0, NQ_, 256);
}

// fused soff/toff/attn-weight projections from qc. grid.y = 12.
__global__ __launch_bounds__(256, 2) void gemm_proj3(
        const float* __restrict__ qc,
        const float* __restrict__ sw, const float* __restrict__ sb,
        const float* __restrict__ tw, const float* __restrict__ tb,
        const float* __restrict__ aw, const float* __restrict__ ab,
        float* __restrict__ so, float* __restrict__ to, float* __restrict__ ao) {
    __shared__ __align__(16) us As[64 * 40];
    __shared__ __align__(16) us Bs[64 * 40];
    int y = blockIdx.y, g = y >> 2, cn0 = (y & 3) * 64;
    const float* W; const float* bias; float* O;
    if (g == 0)      { W = sw; bias = sb; O = so; }
    else if (g == 1) { W = tw; bias = tb; O = to; }
    else             { W = aw; bias = ab; O = ao; }
    gemm64_core<false>(As, Bs, qc, W + (size_t)cn0 * 256, bias + cn0, O, 256, cn0, NQ_, 256);
}

// ---------------------------------------------------------------------------
// value projection: block tile 64 rows x FULL 256 cols (A read exactly once).
// src (97920 x 256) fp32, W (256 x 256), out bf16 (T,LIN,NH,HD).
// ---------------------------------------------------------------------------
__global__ __launch_bounds__(256, 2) void gemm_value(
        const float* __restrict__ src, const float* __restrict__ W,
        const float* __restrict__ bias, us* __restrict__ out) {
    constexpr int LDA = 40;
    __shared__ __align__(16) us As[64 * LDA];     // 5.1 KB
    __shared__ __align__(16) us Bs[256 * LDA];    // 20.5 KB
    int tid = threadIdx.x, wave = tid >> 6, lane = tid & 63;
    int bm = blockIdx.x * 64;
    int fr = lane & 15, quad = lane >> 4;
    f32x4 acc[4][4];
    #pragma unroll
    for (int i = 0; i < 4; ++i)
        #pragma unroll
        for (int j = 0; j < 4; ++j) { f32x4 z = {0.f,0.f,0.f,0.f}; acc[i][j] = z; }

    for (int k0 = 0; k0 < 256; k0 += 32) {
        float4 av[2], bv[8];
        #pragma unroll
        for (int i = 0; i < 2; ++i) {
            int f = i * 256 + tid;
            av[i] = *(const float4*)(src + (size_t)(bm + (f >> 3)) * 256 + k0 + (f & 7) * 4);
        }
        #pragma unroll
        for (int i = 0; i < 8; ++i) {
            int f = i * 256 + tid;
            bv[i] = *(const float4*)(W + (size_t)(f >> 3) * 256 + k0 + (f & 7) * 4);
        }
        __syncthreads();
        #pragma unroll
        for (int i = 0; i < 2; ++i) {
            int f = i * 256 + tid;
            uint2 p; p.x = pack2(av[i].x, av[i].y); p.y = pack2(av[i].z, av[i].w);
            *(uint2*)(As + (f >> 3) * LDA + (f & 7) * 4) = p;
        }
        #pragma unroll
        for (int i = 0; i < 8; ++i) {
            int f = i * 256 + tid;
            uint2 p; p.x = pack2(bv[i].x, bv[i].y); p.y = pack2(bv[i].z, bv[i].w);
            *(uint2*)(Bs + (f >> 3) * LDA + (f & 7) * 4) = p;
        }
        __syncthreads();
        bf16x8 af[4], bfv[4];
        #pragma unroll
        for (int mt = 0; mt < 4; ++mt)
            af[mt] = *(const bf16x8*)(As + (mt * 16 + fr) * LDA + quad * 8);
        #pragma unroll
        for (int nt = 0; nt < 4; ++nt)
            bfv[nt] = *(const bf16x8*)(Bs + (wave * 64 + nt * 16 + fr) * LDA + quad * 8);
        #pragma unroll
        for (int mt = 0; mt < 4; ++mt)
            #pragma unroll
            for (int nt = 0; nt < 4; ++nt)
                acc[mt][nt] = __builtin_amdgcn_mfma_f32_16x16x32_bf16(af[mt], bfv[nt], acc[mt][nt], 0, 0, 0);
    }
    #pragma unroll
    for (int nt = 0; nt < 4; ++nt) {
        int n = wave * 64 + nt * 16 + fr;
        float bs = bias[n];
        #pragma unroll
        for (int mt = 0; mt < 4; ++mt) {
            int mbase = bm + mt * 16 + quad * 4;
            #pragma unroll
            for (int r = 0; r < 4; ++r)
                out[(size_t)(mbase + r) * 256 + n] = f2b(acc[mt][nt][r] + bs);
        }
    }
}

// ---------------------------------------------------------------------------
// Self-attention (unchanged from round 2 — verified correct)
// ---------------------------------------------------------------------------
__global__ __launch_bounds__(256) void attn_kernel(
        const float* __restrict__ qk, const float* __restrict__ vb,
        float* __restrict__ sain) {
    __shared__ uint32 Ksu[300 * 17];
    __shared__ uint32 Vsu[300 * 17];
    __shared__ float  Qs[32 * 32];
    __shared__ float  ps[4][304];
    int t = blockIdx.x / NH_, h = blockIdx.x % NH_;
    int q0 = blockIdx.y * 32;
    int tid = threadIdx.x;

    for (int idx = tid; idx < 300 * 16; idx += 256) {
        int row = idx >> 4, cc = idx & 15;
        float2 kv = *(const float2*)(qk + (size_t)(t * 300 + row) * 512 + 256 + h * 32 + 2 * cc);
        float2 vv = *(const float2*)(vb + (size_t)(t * 300 + row) * 256 + h * 32 + 2 * cc);
        Ksu[row * 17 + cc] = pack2(kv.x, kv.y);
        Vsu[row * 17 + cc] = pack2(vv.x, vv.y);
    }
    for (int idx = tid; idx < 1024; idx += 256) {
        int row = idx >> 5, d = idx & 31;
        int q = q0 + row;
        Qs[idx] = (q < 300) ? qk[(size_t)(t * 300 + q) * 512 + h * 32 + d] : 0.f;
    }
    __syncthreads();

    int wavei = tid >> 6, lane = tid & 63;
    const float scale = 0.17677669529663687f;  // 1/sqrt(32)

    for (int i = 0; i < 8; ++i) {
        int q = q0 + wavei * 8 + i;
        int ql = wavei * 8 + i;
        float qv[32];
        #pragma unroll
        for (int d = 0; d < 32; ++d) qv[d] = Qs[ql * 32 + d];

        float sc[5], mx = -1e30f;
        #pragma unroll
        for (int m = 0; m < 5; ++m) {
            int k = lane + 64 * m;
            float s = -1e30f;
            if (k < 300) {
                s = 0.f;
                #pragma unroll
                for (int dd = 0; dd < 16; ++dd) {
                    uint32 u = Ksu[k * 17 + dd];
                    s += qv[2 * dd]     * b2f((us)u)
                       + qv[2 * dd + 1] * b2f((us)(u >> 16));
                }
                s *= scale;
            }
            sc[m] = s; mx = fmaxf(mx, s);
        }
        #pragma unroll
        for (int off = 1; off < 64; off <<= 1) mx = fmaxf(mx, __shfl_xor(mx, off));
        float sum = 0.f;
        #pragma unroll
        for (int m = 0; m < 5; ++m) {
            int k = lane + 64 * m;
            float ev = (k < 300) ? __expf(sc[m] - mx) : 0.f;
            if (k < 300) ps[wavei][k] = ev;
            sum += ev;
        }
        #pragma unroll
        for (int off = 1; off < 64; off <<= 1) sum += __shfl_xor(sum, off);
        float inv = 1.f / sum;
        __syncthreads();

        int e16 = lane & 15, kh = lane >> 4;
        float ox = 0.f, oy = 0.f;
        int kbeg = kh * 75;
        for (int k = kbeg; k < kbeg + 75; ++k) {
            float p = ps[wavei][k];
            uint32 u = Vsu[k * 17 + e16];
            ox += p * b2f((us)u);
            oy += p * b2f((us)(u >> 16));
        }
        ox += __shfl_xor(ox, 16); ox += __shfl_xor(ox, 32);
        oy += __shfl_xor(oy, 16); oy += __shfl_xor(oy, 32);
        if (q < 300 && kh == 0) {
            *(float2*)(sain + (size_t)(t * 300 + q) * 256 + h * 32 + 2 * e16)
                = make_float2(ox * inv, oy * inv);
        }
        __syncthreads();
    }
}

// ---------------------------------------------------------------------------
// aw softmax + deformable bilinear sampling (unchanged — verified correct)
// ---------------------------------------------------------------------------
__global__ __launch_bounds__(256) void sample_kernel(
        const float* __restrict__ awl,   const float* __restrict__ refp,
        const float* __restrict__ cfo,   const float* __restrict__ ofo,
        const float* __restrict__ soffo, const float* __restrict__ toffo,
        const us* __restrict__ value, float* __restrict__ samp) {
    const int HL[4] = {96, 48, 24, 12};
    const int WL[4] = {128, 64, 32, 16};
    const int ST[4] = {0, 12288, 15360, 16128};
    int b = blockIdx.x;
    int t = b / LQ_;
    int tid = threadIdx.x, h = tid >> 5, d = tid & 31;
    size_t row = (size_t)b;

    float logit = awl[row * 256 + h * 32 + d];
    float mx = logit;
    #pragma unroll
    for (int off = 16; off >= 1; off >>= 1) mx = fmaxf(mx, __shfl_xor(mx, off, 32));
    float e = __expf(logit - mx);
    float s = e;
    #pragma unroll
    for (int off = 16; off >= 1; off >>= 1) s += __shfl_xor(s, off, 32);
    float myw = e / s;

    float acc = 0.f;
    for (int smp = 0; smp < 32; ++smp) {
        int l = smp >> 3, j = smp & 7;
        float wgt = __shfl(myw, smp, 32);
        int Hl = HL[l], Wl = WL[l], st = ST[l];
        float rx = refp[(row * 4 + l) * 2 + 0];
        float ry = refp[(row * 4 + l) * 2 + 1];
        float lx, ly; int frame;
        if (j < 4) {
            lx = rx + cfo[(row * 4 + l) * 2 + 0]
               + soffo[row * 256 + h * 32 + l * 8 + j * 2 + 0] / (float)Wl;
            ly = ry + cfo[(row * 4 + l) * 2 + 1]
               + soffo[row * 256 + h * 32 + l * 8 + j * 2 + 1] / (float)Hl;
            frame = t;
        } else {
            int wi = (j - 4) >> 1, p = (j - 4) & 1;
            lx = rx + ofo[((row * 2 + wi) * 4 + l) * 2 + 0]
               + toffo[row * 256 + h * 32 + l * 8 + wi * 4 + p * 2 + 0] / (float)Wl;
            ly = ry + ofo[((row * 2 + wi) * 4 + l) * 2 + 1]
               + toffo[row * 256 + h * 32 + l * 8 + wi * 4 + p * 2 + 1] / (float)Hl;
            frame = t + (wi == 0 ? -1 : 1);
            frame = frame < 0 ? 0 : (frame > T_ - 1 ? T_ - 1 : frame);
        }
        float x = lx * (float)Wl - 0.5f, y = ly * (float)Hl - 0.5f;
        float xf = floorf(x), yf = floorf(y);
        float wx = x - xf, wy = y - yf;
        int x0 = (int)xf, y0 = (int)yf;
        float sacc = 0.f;
        size_t base = ((size_t)frame * LIN_ + st) * 256 + h * 32 + d;
        #pragma unroll
        for (int cy = 0; cy < 2; ++cy) {
            int yi = y0 + cy;
            if (yi < 0 || yi >= Hl) continue;
            float wyv = cy ? wy : 1.f - wy;
            #pragma unroll
            for (int cx = 0; cx < 2; ++cx) {
                int xi = x0 + cx;
                if (xi < 0 || xi >= Wl) continue;
                float wv = wyv * (cx ? wx : 1.f - wx);
                sacc += wv * b2f(value[base + (size_t)(yi * Wl + xi) * 256]);
            }
        }
        acc += wgt * sacc;
    }
    samp[row * 256 + h * 32 + d] = acc;
}

// ---------------------------------------------------------------------------
// out = LN(x + y)*g + b ; optional out2 = out + pos. (unchanged)
// ---------------------------------------------------------------------------
__global__ __launch_bounds__(256) void ln_kernel(
        const float* __restrict__ x, const float* __restrict__ y,
        const float* __restrict__ g, const float* __restrict__ bb,
        float* __restrict__ out,
        const float* __restrict__ pos, float* __restrict__ out2) {
    int row = blockIdx.x, c = threadIdx.x;
    size_t idx = (size_t)row * 256 + c;
    float v = x[idx] + y[idx];
    float s = v;
    #pragma unroll
    for (int off = 1; off < 64; off <<= 1) s += __shfl_xor(s, off);
    __shared__ float red[4];
    int wv = c >> 6;
    if ((c & 63) == 0) red[wv] = s;
    __syncthreads();
    float mean = (red[0] + red[1] + red[2] + red[3]) * (1.0f / 256.0f);
    float dv = v - mean;
    float s2 = dv * dv;
    #pragma unroll
    for (int off = 1; off < 64; off <<= 1) s2 += __shfl_xor(s2, off);
    __syncthreads();
    if ((c & 63) == 0) red[wv] = s2;
    __syncthreads();
    float var = (red[0] + red[1] + red[2] + red[3]) * (1.0f / 256.0f);
    float o = dv * rsqrtf(var + 1e-5f) * g[c] + bb[c];
    out[idx] = o;
    if (out2) out2[idx] = o + pos[idx];
}

// ---------------------------------------------------------------------------
extern "C" void kernel_launch(void* const* d_in, const int* in_sizes, int n_in,
                              void* d_out, int out_size, void* d_ws, size_t ws_size,
                              hipStream_t stream) {
    (void)in_sizes; (void)n_in; (void)out_size; (void)ws_size;
    typedef const float* cfp;
    cfp tgt   = (cfp)d_in[0];
    cfp qpos  = (cfp)d_in[1];
    cfp refp  = (cfp)d_in[2];
    cfp cfo   = (cfp)d_in[3];
    cfp ofo   = (cfp)d_in[4];
    cfp src   = (cfp)d_in[5];
    cfp in_proj_w = (cfp)d_in[9];
    cfp in_proj_b = (cfp)d_in[10];
    cfp sa_out_w  = (cfp)d_in[11];
    cfp sa_out_b  = (cfp)d_in[12];
    cfp n1g = (cfp)d_in[13], n1b = (cfp)d_in[14];
    cfp n2g = (cfp)d_in[15], n2b = (cfp)d_in[16];
    cfp n3g = (cfp)d_in[17], n3b = (cfp)d_in[18];
    cfp value_w = (cfp)d_in[19], value_b = (cfp)d_in[20];
    cfp soff_w = (cfp)d_in[21], soff_b = (cfp)d_in[22];
    cfp toff_w = (cfp)d_in[23], toff_b = (cfp)d_in[24];
    cfp attn_w = (cfp)d_in[25], attn_b = (cfp)d_in[26];
    cfp cross_w = (cfp)d_in[27], cross_b = (cfp)d_in[28];
    cfp lin1_w = (cfp)d_in[29], lin1_b = (cfp)d_in[30];
    cfp lin2_w = (cfp)d_in[31], lin2_b = (cfp)d_in[32];

    // ---- workspace arena (lifetime-aliased; launches are stream-ordered)
    char* wp = (char*)d_ws;
    const size_t ROWB = (size_t)NQ_ * 256 * 4;
    us* value = (us*)wp;  wp += (size_t)T_ * LIN_ * 256 * 2;   // bf16, 25 MB
    float* bigreg = (float*)wp;  wp += 4 * ROWB;               // qin|qkb|vbuf, then ff1
    float* qin  = bigreg;
    float* qkb  = bigreg + (size_t)NQ_ * 256;
    float* vbuf = bigreg + (size_t)NQ_ * 768;
    float* ff1  = bigreg;
    float* sain   = (float*)wp; wp += ROWB;   float* awl    = sain;
    float* sap    = (float*)wp; wp += ROWB;   float* soffo  = sap;
    float* tgt2   = (float*)wp; wp += ROWB;   float* ff2    = tgt2;
    float* qc     = (float*)wp; wp += ROWB;   float* samp   = qc;
    float* toffo  = (float*)wp; wp += ROWB;
    float* crossp = (float*)wp; wp += ROWB;
    float* tgt3   = (float*)wp; wp += ROWB;

    dim3 blk(256);
    const int mb = (NQ_ + 63) / 64;  // 29

    add_f32<<<dim3((NQ_ * 64 + 255) / 256), blk, 0, stream>>>(
        (const float4*)tgt, (const float4*)qpos, (float4*)qin, NQ_ * 64);
    gemm_qkv<<<dim3(mb, 12), blk, 0, stream>>>(qin, tgt, in_proj_w, in_proj_b, qkb, vbuf);
    attn_kernel<<<dim3(T_ * NH_, 10), blk, 0, stream>>>(qkb, vbuf, sain);
    gemm_std<false><<<dim3(mb, 4), blk, 0, stream>>>(sain, sa_out_w, sa_out_b, sap, NQ_, 256, 256);
    ln_kernel<<<dim3(NQ_), blk, 0, stream>>>(tgt, sap, n2g, n2b, tgt2, qpos, qc);
    gemm_proj3<<<dim3(mb, 12), blk, 0, stream>>>(qc, soff_w, soff_b, toff_w, toff_b,
                                                 attn_w, attn_b, soffo, toffo, awl);
    gemm_value<<<dim3((T_ * LIN_) / 64), blk, 0, stream>>>(src, value_w, value_b, value);
    sample_kernel<<<dim3(NQ_), blk, 0, stream>>>(awl, refp, cfo, ofo, soffo, toffo, value, samp);
    gemm_std<false><<<dim3(mb, 4), blk, 0, stream>>>(samp, cross_w, cross_b, crossp, NQ_, 256, 256);
    ln_kernel<<<dim3(NQ_), blk, 0, stream>>>(tgt2, crossp, n1g, n1b, tgt3, nullptr, nullptr);
    gemm_std<true><<<dim3(mb, 16), blk, 0, stream>>>(tgt3, lin1_w, lin1_b, ff1, NQ_, 1024, 256);
    gemm_std<false><<<dim3(mb, 4), blk, 0, stream>>>(ff1, lin2_w, lin2_b, ff2, NQ_, 256, 1024);
    ln_kernel<<<dim3(NQ_), blk, 0, stream>>>(tgt3, ff2, n3g, n3b, (float*)d_out, nullptr, nullptr);
}